// Round 2
// baseline (24925.266 us; speedup 1.0000x reference)
//
#include <hip/hip_runtime.h>
#include <hip/hip_bf16.h>

#define N_   64
#define T_   1024
#define IN_  64
#define H1_  512
#define H2_  256
#define K1_  576    // IN_ + H1_
#define K2_  768    // H1_ + H2_
#define NBLK 24     // 16 layer-1 blocks + 8 layer-2 blocks

typedef __bf16 bf16x8 __attribute__((ext_vector_type(8)));
typedef float  f32x4  __attribute__((ext_vector_type(4)));
typedef unsigned int u32x4 __attribute__((ext_vector_type(4)));
typedef unsigned short u16x8 __attribute__((ext_vector_type(8)));
typedef __hip_bfloat16 bf16_t;

// ---------------- workspace layout (bytes) ----------------
#define OFF_H1B   196608u       // 2 * 64*512*2 = 131072
#define OFF_H2B   327680u       // 2 * 64*256*2 = 65536
#define OFF_BAR   393216u       // barrier cnt (+0) / sense (+128)
#define ZERO_BYTES 393472u
#define OFF_XB    393472u       // 64*1024*64*2 = 8388608
#define OFF_W1    8782080u      // 2048*576*2 = 2359296
#define OFF_W2    11141376u     // 1024*768*2 = 1572864
#define OFF_B1    12714240u     // 2048*4
#define OFF_B2    12722432u     // 1024*4
#define OFF_FC1W  12726528u     // 128*512*2 = 131072
#define OFF_FC2W  12857600u     // 64*128*2 = 16384
#define OFF_HS2   12873984u     // 64*1024*256*2 = 33554432
#define OFF_HST   46428416u     // 33554432  -> end ~80 MB

__device__ __forceinline__ bf16x8 ld16(const bf16_t* p) {
  u32x4 u = *reinterpret_cast<const u32x4*>(p);
  return __builtin_bit_cast(bf16x8, u);
}
__device__ __forceinline__ f32x4 mfma_bf16(bf16x8 a, bf16x8 b, f32x4 c) {
  return __builtin_amdgcn_mfma_f32_16x16x32_bf16(a, b, c, 0, 0, 0);
}
__device__ __forceinline__ float sigf(float x) { return 1.f / (1.f + __expf(-x)); }
__device__ __forceinline__ float tanh_fast(float x) {
  float e = __expf(-2.f * fabsf(x));
  float r = (1.f - e) / (1.f + e);
  return x < 0.f ? -r : r;
}
__device__ __forceinline__ void st_bf16_nt(bf16_t* p, float v) {
  __hip_bfloat16 b = __float2bfloat16(v);
  unsigned short u = *reinterpret_cast<unsigned short*>(&b);
  __builtin_nontemporal_store(u, reinterpret_cast<unsigned short*>(p));
}

// ---------------- setup: bf16 conversion / packing ----------------
__global__ void setup_kernel(const float* __restrict__ x,
    const float* __restrict__ Wih1, const float* __restrict__ Whh1,
    const float* __restrict__ bih1, const float* __restrict__ bhh1,
    const float* __restrict__ Wih2, const float* __restrict__ Whh2,
    const float* __restrict__ bih2, const float* __restrict__ bhh2,
    const float* __restrict__ fc1w, const float* __restrict__ fc2w,
    char* __restrict__ ws)
{
  bf16_t* xb = (bf16_t*)(ws + OFF_XB);
  bf16_t* w1 = (bf16_t*)(ws + OFF_W1);
  bf16_t* w2 = (bf16_t*)(ws + OFF_W2);
  float*  b1 = (float*)(ws + OFF_B1);
  float*  b2 = (float*)(ws + OFF_B2);
  bf16_t* f1 = (bf16_t*)(ws + OFF_FC1W);
  bf16_t* f2 = (bf16_t*)(ws + OFF_FC2W);
  const long E0 = 4194304, E1 = E0 + 1179648, E2 = E1 + 786432,
             E3 = E2 + 2048, E4 = E3 + 1024, E5 = E4 + 65536, E6 = E5 + 8192;
  for (long i = blockIdx.x * (long)blockDim.x + threadIdx.x; i < E6;
       i += (long)gridDim.x * blockDim.x) {
    if (i < E0) {
      xb[i] = __float2bfloat16(x[i]);
    } else if (i < E1) {                       // W1[j][k] = concat(Wih1, Whh1) rows
      long idx = i - E0; long j = idx / 576, k = idx % 576;
      float v = (k < 64) ? Wih1[j * 64 + k] : Whh1[j * 512 + (k - 64)];
      w1[idx] = __float2bfloat16(v);
    } else if (i < E2) {                       // W2[j][k] = concat(Wih2, Whh2)
      long idx = i - E1; long j = idx / 768, k = idx % 768;
      float v = (k < 512) ? Wih2[j * 512 + k] : Whh2[j * 256 + (k - 512)];
      w2[idx] = __float2bfloat16(v);
    } else if (i < E3) {
      long idx = i - E2; b1[idx] = bih1[idx] + bhh1[idx];
    } else if (i < E4) {
      long idx = i - E3; b2[idx] = bih2[idx] + bhh2[idx];
    } else if (i < E5) {
      long idx = i - E4; f1[idx] = __float2bfloat16(fc1w[idx]);
    } else {                                   // fc2 padded to 64 rows
      long idx = i - E5; long j = idx / 128, k = idx % 128;
      f2[idx] = __float2bfloat16(j < 51 ? fc2w[j * 128 + k] : 0.f);
    }
  }
}

// ---------------- grid barrier: single acq_rel RMW per block per step ----------------
// Release part of the RMW flushes this block's h-writes past L2 (coherence point);
// spinners' ACQUIRE load (or last block's acq_rel RMW) invalidates stale lines.
__device__ __forceinline__ void grid_barrier(unsigned* cnt, unsigned* sense, unsigned gen) {
  __syncthreads();
  if (threadIdx.x == 0) {
    unsigned old = __hip_atomic_fetch_add(cnt, 1u, __ATOMIC_ACQ_REL, __HIP_MEMORY_SCOPE_AGENT);
    if (old == (unsigned)(NBLK - 1)) {
      __hip_atomic_store(cnt, 0u, __ATOMIC_RELAXED, __HIP_MEMORY_SCOPE_AGENT);
      __hip_atomic_store(sense, gen, __ATOMIC_RELEASE, __HIP_MEMORY_SCOPE_AGENT);
    } else {
      unsigned s;
      do {
        __builtin_amdgcn_s_sleep(1);
        s = __hip_atomic_load(sense, __ATOMIC_ACQUIRE, __HIP_MEMORY_SCOPE_AGENT);
      } while (s < gen);
    }
  }
  __syncthreads();
}

// ---------------- persistent LSTM kernel (both layers, pipelined) ----------------
__global__ __launch_bounds__(256, 1) void lstm_kernel(char* __restrict__ ws,
                                                      float* __restrict__ dout)
{
  const bf16_t* xb  = (const bf16_t*)(ws + OFF_XB);
  const bf16_t* W1  = (const bf16_t*)(ws + OFF_W1);
  const bf16_t* W2  = (const bf16_t*)(ws + OFF_W2);
  const float*  b1  = (const float*)(ws + OFF_B1);
  const float*  b2  = (const float*)(ws + OFF_B2);
  bf16_t* h1b = (bf16_t*)(ws + OFF_H1B);
  bf16_t* h2b = (bf16_t*)(ws + OFF_H2B);
  bf16_t* hs2 = (bf16_t*)(ws + OFF_HS2);
  unsigned* bcnt   = (unsigned*)(ws + OFF_BAR);
  unsigned* bsense = bcnt + 32;

  __shared__ float gbuf[4][64][32];   // 32 KB: gate results (fp32) for 64 batch x 32 units

  const int tid  = threadIdx.x;
  const int wave = tid >> 6;
  const int lane = tid & 63;
  const int l15  = lane & 15;
  const int quad = lane >> 4;
  const int wg   = blockIdx.x;
  const f32x4 z = {0.f, 0.f, 0.f, 0.f};

  if (wg < 16) {
    // ---- LSTM layer 1: block owns 32 units [wg*32, wg*32+32), wave = gate
    const int u0 = wg * 32;
    bf16x8 wf[18][2];
    #pragma unroll
    for (int i = 0; i < 18; ++i) {
      int k = (i < 2) ? i * 32 : 64 + (i - 2) * 32;
      #pragma unroll
      for (int nt = 0; nt < 2; ++nt)
        wf[i][nt] = ld16(W1 + (size_t)(wave * H1_ + u0 + nt * 16 + l15) * K1_ + k + quad * 8);
    }
    int ub[8], uu[8];
    float bi[8], bff[8], bg[8], bo[8], creg[8];
    #pragma unroll
    for (int r = 0; r < 8; ++r) {
      int idx = tid + r * 256;
      ub[r] = idx >> 5;
      uu[r] = u0 + (idx & 31);
      bi[r]  = b1[uu[r]];
      bff[r] = b1[H1_ + uu[r]];
      bg[r]  = b1[2 * H1_ + uu[r]];
      bo[r]  = b1[3 * H1_ + uu[r]];
      creg[r] = 0.f;
    }
    #pragma unroll 1
    for (int tau = 0; tau <= T_; ++tau) {
      const int t = tau;
      if (t < T_) {
        const bf16_t* hprev = h1b + ((t & 1) ^ 1) * (N_ * H1_);
        bf16_t* hcur = h1b + (t & 1) * (N_ * H1_);
        f32x4 acc[4][2];
        #pragma unroll
        for (int mt = 0; mt < 4; ++mt) { acc[mt][0] = z; acc[mt][1] = z; }
        #pragma unroll
        for (int ki = 0; ki < 2; ++ki) {
          #pragma unroll
          for (int mt = 0; mt < 4; ++mt) {
            bf16x8 aw = ld16(xb + ((size_t)(mt * 16 + l15) * T_ + t) * IN_ + ki * 32 + quad * 8);
            #pragma unroll
            for (int nt = 0; nt < 2; ++nt)
              acc[mt][nt] = mfma_bf16(aw, wf[ki][nt], acc[mt][nt]);
          }
        }
        #pragma unroll
        for (int ki = 0; ki < 16; ++ki) {
          #pragma unroll
          for (int mt = 0; mt < 4; ++mt) {
            bf16x8 aw = ld16(hprev + (size_t)(mt * 16 + l15) * H1_ + ki * 32 + quad * 8);
            #pragma unroll
            for (int nt = 0; nt < 2; ++nt)
              acc[mt][nt] = mfma_bf16(aw, wf[2 + ki][nt], acc[mt][nt]);
          }
        }
        #pragma unroll
        for (int mt = 0; mt < 4; ++mt)
          #pragma unroll
          for (int nt = 0; nt < 2; ++nt)
            #pragma unroll
            for (int r = 0; r < 4; ++r)
              gbuf[wave][mt * 16 + quad * 4 + r][nt * 16 + l15] = acc[mt][nt][r];
        __syncthreads();
        #pragma unroll
        for (int r = 0; r < 8; ++r) {
          int b = ub[r], ug = uu[r], u = ug - u0;
          float iv = sigf(gbuf[0][b][u] + bi[r]);
          float fv = sigf(gbuf[1][b][u] + bff[r]);
          float gv = tanh_fast(gbuf[2][b][u] + bg[r]);
          float ov = sigf(gbuf[3][b][u] + bo[r]);
          float c = fv * creg[r] + iv * gv;
          creg[r] = c;
          float h = ov * tanh_fast(c);
          st_bf16_nt(hcur + (size_t)b * H1_ + ug, h);
          if (t == T_ - 1) {
            dout[65536 + b * H1_ + ug] = h;
            dout[98304 + b * H1_ + ug] = c;
          }
        }
        __syncthreads();   // gbuf reads done before next step overwrites
      }
      grid_barrier(bcnt, bsense, (unsigned)(tau + 1));
    }
  } else {
    // ---- LSTM layer 2 (one step behind): block owns 32 units
    const int wg2 = wg - 16;
    const int u0 = wg2 * 32;
    bf16x8 wf[24][2];
    #pragma unroll
    for (int i = 0; i < 24; ++i) {
      int k = (i < 16) ? i * 32 : 512 + (i - 16) * 32;
      #pragma unroll
      for (int nt = 0; nt < 2; ++nt)
        wf[i][nt] = ld16(W2 + (size_t)(wave * H2_ + u0 + nt * 16 + l15) * K2_ + k + quad * 8);
    }
    int ub[8], uu[8];
    float bi[8], bff[8], bg[8], bo[8], creg[8];
    #pragma unroll
    for (int r = 0; r < 8; ++r) {
      int idx = tid + r * 256;
      ub[r] = idx >> 5;
      uu[r] = u0 + (idx & 31);
      bi[r]  = b2[uu[r]];
      bff[r] = b2[H2_ + uu[r]];
      bg[r]  = b2[2 * H2_ + uu[r]];
      bo[r]  = b2[3 * H2_ + uu[r]];
      creg[r] = 0.f;
    }
    #pragma unroll 1
    for (int tau = 0; tau <= T_; ++tau) {
      const int t = tau - 1;
      if (t >= 0) {
        const bf16_t* xin   = h1b + (t & 1) * (N_ * H1_);        // h1_t
        const bf16_t* hprev = h2b + ((t & 1) ^ 1) * (N_ * H2_);
        bf16_t* hcur = h2b + (t & 1) * (N_ * H2_);
        f32x4 acc[4][2];
        #pragma unroll
        for (int mt = 0; mt < 4; ++mt) { acc[mt][0] = z; acc[mt][1] = z; }
        #pragma unroll
        for (int ki = 0; ki < 16; ++ki) {
          #pragma unroll
          for (int mt = 0; mt < 4; ++mt) {
            bf16x8 aw = ld16(xin + (size_t)(mt * 16 + l15) * H1_ + ki * 32 + quad * 8);
            #pragma unroll
            for (int nt = 0; nt < 2; ++nt)
              acc[mt][nt] = mfma_bf16(aw, wf[ki][nt], acc[mt][nt]);
          }
        }
        #pragma unroll
        for (int ki = 0; ki < 8; ++ki) {
          #pragma unroll
          for (int mt = 0; mt < 4; ++mt) {
            bf16x8 aw = ld16(hprev + (size_t)(mt * 16 + l15) * H2_ + ki * 32 + quad * 8);
            #pragma unroll
            for (int nt = 0; nt < 2; ++nt)
              acc[mt][nt] = mfma_bf16(aw, wf[16 + ki][nt], acc[mt][nt]);
          }
        }
        #pragma unroll
        for (int mt = 0; mt < 4; ++mt)
          #pragma unroll
          for (int nt = 0; nt < 2; ++nt)
            #pragma unroll
            for (int r = 0; r < 4; ++r)
              gbuf[wave][mt * 16 + quad * 4 + r][nt * 16 + l15] = acc[mt][nt][r];
        __syncthreads();
        #pragma unroll
        for (int r = 0; r < 8; ++r) {
          int b = ub[r], ug = uu[r], u = ug - u0;
          float iv = sigf(gbuf[0][b][u] + bi[r]);
          float fv = sigf(gbuf[1][b][u] + bff[r]);
          float gv = tanh_fast(gbuf[2][b][u] + bg[r]);
          float ov = sigf(gbuf[3][b][u] + bo[r]);
          float c = fv * creg[r] + iv * gv;
          creg[r] = c;
          float h = ov * tanh_fast(c);
          st_bf16_nt(hcur + (size_t)b * H2_ + ug, h);
          st_bf16_nt(hs2 + ((size_t)b * T_ + t) * H2_ + ug, h);
          if (t == T_ - 1) {
            dout[131072 + b * H2_ + ug] = h;
            dout[147456 + b * H2_ + ug] = c;
          }
        }
        __syncthreads();
      }
      grid_barrier(bcnt, bsense, (unsigned)(tau + 1));
    }
  }
}

// ---------------- hs2 [n][t][ch] -> hsT [n][ch][t]  (LDS tile transpose) ----------------
__global__ __launch_bounds__(256) void transpose_kernel(char* __restrict__ ws)
{
  const unsigned short* src = (const unsigned short*)(ws + OFF_HS2);
  unsigned short* dst = (unsigned short*)(ws + OFF_HST);
  __shared__ unsigned short tile[64][72];
  const int bx = blockIdx.x;
  const int n  = bx >> 6;
  const int tt = (bx & 63) >> 2;
  const int cb = bx & 3;
  const int t0 = tt * 64, c0 = cb * 64;
  const int tid = threadIdx.x;
  const int row = tid >> 3;          // 0..31
  const int colg = (tid & 7) * 8;    // 0,8,..,56
  #pragma unroll
  for (int i = 0; i < 2; ++i) {
    int r = row + i * 32;
    u16x8 v = *reinterpret_cast<const u16x8*>(src + ((size_t)n * T_ + t0 + r) * H2_ + c0 + colg);
    *reinterpret_cast<u16x8*>(&tile[r][colg]) = v;
  }
  __syncthreads();
  #pragma unroll
  for (int i = 0; i < 2; ++i) {
    int crow = row + i * 32;
    u16x8 v;
    #pragma unroll
    for (int j = 0; j < 8; ++j) v[j] = tile[colg + j][crow];
    *reinterpret_cast<u16x8*>(dst + ((size_t)n * H2_ + c0 + crow) * T_ + t0 + colg) = v;
  }
}

// ---------------- flash attention + fused FC head ----------------
__global__ __launch_bounds__(256, 2) void attn_fc_kernel(
    const char* __restrict__ ws,
    const float* __restrict__ fc1b, const float* __restrict__ fc2b,
    const float* __restrict__ fc3w, const float* __restrict__ fc3b,
    float* __restrict__ dout)
{
  const bf16_t* hs2 = (const bf16_t*)(ws + OFF_HS2);
  const bf16_t* hsT = (const bf16_t*)(ws + OFF_HST);
  const bf16_t* f1w = (const bf16_t*)(ws + OFF_FC1W);
  const bf16_t* f2w = (const bf16_t*)(ws + OFF_FC2W);

  __shared__ __align__(16) unsigned char smem[51200];
  bf16_t* ctxlds = (bf16_t*)smem;             // [64][264]
  bf16_t* act1   = (bf16_t*)(smem + 33792);   // [64][136]
  bf16_t* plds   = (bf16_t*)(smem + 33792);   // wave w: +w*1152, [16][72]
  float*  act2   = (float*)smem;              // [64][68]

  const int tid  = threadIdx.x;
  const int wave = tid >> 6, lane = tid & 63;
  const int l15  = lane & 15, quad = lane >> 4;
  const int n  = blockIdx.x >> 4;
  const int qt = blockIdx.x & 15;
  const int q0 = qt * 64;
  const f32x4 z = {0.f, 0.f, 0.f, 0.f};

  bf16x8 aq[8];
  #pragma unroll
  for (int ks = 0; ks < 8; ++ks)
    aq[ks] = ld16(hs2 + ((size_t)n * T_ + q0 + wave * 16 + l15) * H2_ + ks * 32 + quad * 8);

  f32x4 o[16];
  #pragma unroll
  for (int ct = 0; ct < 16; ++ct) o[ct] = z;
  float m_run[4], l_run[4];
  #pragma unroll
  for (int r = 0; r < 4; ++r) { m_run[r] = -1e30f; l_run[r] = 0.f; }

  bf16_t* pw = plds + wave * 1152;

  #pragma unroll 1
  for (int st = 0; st <= qt; ++st) {
    const int s0 = st * 64;
    f32x4 sc[4] = {z, z, z, z};
    #pragma unroll
    for (int ks = 0; ks < 8; ++ks) {
      #pragma unroll
      for (int nt = 0; nt < 4; ++nt) {
        bf16x8 bk = ld16(hs2 + ((size_t)n * T_ + s0 + nt * 16 + l15) * H2_ + ks * 32 + quad * 8);
        sc[nt] = mfma_bf16(aq[ks], bk, sc[nt]);
      }
    }
    if (st == qt) {
      int qg = q0 + wave * 16 + quad * 4;
      #pragma unroll
      for (int nt = 0; nt < 4; ++nt) {
        int sg = s0 + nt * 16 + l15;
        #pragma unroll
        for (int r = 0; r < 4; ++r)
          if (sg > qg + r) sc[nt][r] = -1e30f;
      }
    }
    float alpha[4];
    #pragma unroll
    for (int r = 0; r < 4; ++r) {
      float tm = fmaxf(fmaxf(sc[0][r], sc[1][r]), fmaxf(sc[2][r], sc[3][r]));
      tm = fmaxf(tm, __shfl_xor(tm, 1, 16));
      tm = fmaxf(tm, __shfl_xor(tm, 2, 16));
      tm = fmaxf(tm, __shfl_xor(tm, 4, 16));
      tm = fmaxf(tm, __shfl_xor(tm, 8, 16));
      float mnew = fmaxf(m_run[r], tm);
      alpha[r] = __expf(m_run[r] - mnew);
      m_run[r] = mnew;
      float ts = 0.f;
      #pragma unroll
      for (int nt = 0; nt < 4; ++nt) {
        float p = __expf(sc[nt][r] - mnew);
        sc[nt][r] = p;
        ts += p;
      }
      ts += __shfl_xor(ts, 1, 16);
      ts += __shfl_xor(ts, 2, 16);
      ts += __shfl_xor(ts, 4, 16);
      ts += __shfl_xor(ts, 8, 16);
      l_run[r] = l_run[r] * alpha[r] + ts;
    }
    #pragma unroll
    for (int ct = 0; ct < 16; ++ct)
      #pragma unroll
      for (int r = 0; r < 4; ++r)
        o[ct][r] *= alpha[r];
    #pragma unroll
    for (int nt = 0; nt < 4; ++nt)
      #pragma unroll
      for (int r = 0; r < 4; ++r)
        pw[(quad * 4 + r) * 72 + nt * 16 + l15] = __float2bfloat16(sc[nt][r]);
    #pragma unroll
    for (int ks2 = 0; ks2 < 2; ++ks2) {
      bf16x8 ap = ld16(pw + l15 * 72 + ks2 * 32 + quad * 8);
      #pragma unroll
      for (int ct = 0; ct < 16; ++ct) {
        bf16x8 bv = ld16(hsT + ((size_t)n * H2_ + ct * 16 + l15) * T_ + s0 + ks2 * 32 + quad * 8);
        o[ct] = mfma_bf16(ap, bv, o[ct]);
      }
    }
  }
  float inv[4];
  #pragma unroll
  for (int r = 0; r < 4; ++r) inv[r] = 1.f / l_run[r];
  #pragma unroll
  for (int ct = 0; ct < 16; ++ct)
    #pragma unroll
    for (int r = 0; r < 4; ++r)
      ctxlds[(wave * 16 + quad * 4 + r) * 264 + ct * 16 + l15] =
          __float2bfloat16(o[ct][r] * inv[r]);
  __syncthreads();

  // fc1: K=512 (ctx|hs2) -> 128 ch, wave owns 32 channels
  f32x4 a1[4][2];
  #pragma unroll
  for (int mt = 0; mt < 4; ++mt) { a1[mt][0] = z; a1[mt][1] = z; }
  #pragma unroll
  for (int ks = 0; ks < 16; ++ks) {
    bf16x8 af[4];
    if (ks < 8) {
      #pragma unroll
      for (int mt = 0; mt < 4; ++mt)
        af[mt] = ld16(ctxlds + (mt * 16 + l15) * 264 + ks * 32 + quad * 8);
    } else {
      #pragma unroll
      for (int mt = 0; mt < 4; ++mt)
        af[mt] = ld16(hs2 + ((size_t)n * T_ + q0 + mt * 16 + l15) * H2_ + (ks - 8) * 32 + quad * 8);
    }
    #pragma unroll
    for (int nt = 0; nt < 2; ++nt) {
      bf16x8 bw = ld16(f1w + (size_t)(wave * 32 + nt * 16 + l15) * 512 + ks * 32 + quad * 8);
      #pragma unroll
      for (int mt = 0; mt < 4; ++mt)
        a1[mt][nt] = mfma_bf16(af[mt], bw, a1[mt][nt]);
    }
  }
  #pragma unroll
  for (int mt = 0; mt < 4; ++mt)
    #pragma unroll
    for (int nt = 0; nt < 2; ++nt)
      #pragma unroll
      for (int r = 0; r < 4; ++r) {
        int ch = wave * 32 + nt * 16 + l15;
        float v = a1[mt][nt][r] + fc1b[ch];
        act1[(mt * 16 + quad * 4 + r) * 136 + ch] = __float2bfloat16(fmaxf(v, 0.f));
      }
  __syncthreads();

  // fc2: K=128 -> 51 ch (padded 64), wave owns 16 channels
  f32x4 a2[4] = {z, z, z, z};
  #pragma unroll
  for (int ks = 0; ks < 4; ++ks) {
    bf16x8 bw = ld16(f2w + (wave * 16 + l15) * 128 + ks * 32 + quad * 8);
    #pragma unroll
    for (int mt = 0; mt < 4; ++mt) {
      bf16x8 af = ld16(act1 + (mt * 16 + l15) * 136 + ks * 32 + quad * 8);
      a2[mt] = mfma_bf16(af, bw, a2[mt]);
    }
  }
  #pragma unroll
  for (int mt = 0; mt < 4; ++mt)
    #pragma unroll
    for (int r = 0; r < 4; ++r) {
      int ch = wave * 16 + l15;
      int row = mt * 16 + quad * 4 + r;
      float v = a2[mt][r] + (ch < 51 ? fc2b[ch] : 0.f);
      act2[row * 68 + ch] = fmaxf(v, 0.f);
    }
  __syncthreads();

  // fc3: dot over 51
  if (tid < 64) {
    float s = fc3b[0];
    for (int c = 0; c < 51; ++c) s += act2[tid * 68 + c] * fc3w[c];
    dout[(size_t)n * T_ + q0 + tid] = s;
  }
}

extern "C" void kernel_launch(void* const* d_in, const int* in_sizes, int n_in,
                              void* d_out, int out_size, void* d_ws, size_t ws_size,
                              hipStream_t stream) {
  (void)in_sizes; (void)n_in; (void)out_size; (void)ws_size;
  const float* x    = (const float*)d_in[0];
  const float* Wih1 = (const float*)d_in[1];
  const float* Whh1 = (const float*)d_in[2];
  const float* bih1 = (const float*)d_in[3];
  const float* bhh1 = (const float*)d_in[4];
  const float* Wih2 = (const float*)d_in[5];
  const float* Whh2 = (const float*)d_in[6];
  const float* bih2 = (const float*)d_in[7];
  const float* bhh2 = (const float*)d_in[8];
  const float* fc1w = (const float*)d_in[9];
  const float* fc1b = (const float*)d_in[10];
  const float* fc2w = (const float*)d_in[11];
  const float* fc2b = (const float*)d_in[12];
  const float* fc3w = (const float*)d_in[13];
  const float* fc3b = (const float*)d_in[14];
  char* ws  = (char*)d_ws;
  float* out = (float*)d_out;

  hipMemsetAsync(ws, 0, ZERO_BYTES, stream);
  setup_kernel<<<2048, 256, 0, stream>>>(x, Wih1, Whh1, bih1, bhh1,
                                         Wih2, Whh2, bih2, bhh2, fc1w, fc2w, ws);
  lstm_kernel<<<NBLK, 256, 0, stream>>>(ws, out);
  transpose_kernel<<<4096, 256, 0, stream>>>(ws);
  attn_fc_kernel<<<1024, 256, 0, stream>>>(ws, fc1b, fc2b, fc3w, fc3b, out);
}

// Round 3
// 20498.631 us; speedup vs baseline: 1.2159x; 1.2159x over previous
//
#include <hip/hip_runtime.h>
#include <hip/hip_bf16.h>

#define N_   64
#define T_   1024
#define IN_  64
#define H1_  512
#define H2_  256
#define K1_  576    // IN_ + H1_
#define K2_  768    // H1_ + H2_
#define NBLK 24     // 16 layer-1 blocks + 8 layer-2 blocks
#define NB1  16
#define NB2  8

typedef __bf16 bf16x8 __attribute__((ext_vector_type(8)));
typedef float  f32x4  __attribute__((ext_vector_type(4)));
typedef unsigned int u32x4 __attribute__((ext_vector_type(4)));
typedef unsigned short u16x8 __attribute__((ext_vector_type(8)));
typedef __hip_bfloat16 bf16_t;

// ---------------- workspace layout (bytes) ----------------
#define OFF_H1B   0u            // 4-deep ring: 4 * 64*512*2 = 262144
#define OFF_H2B   262144u       // 2-deep:      2 * 64*256*2 = 65536
#define OFF_BAR   327680u       // barrier/flag area, 2048 B
#define ZERO_BYTES 329728u
#define OFF_XB    329728u       // 64*1024*64*2 = 8388608
#define OFF_W1    8718336u      // 2048*576*2 = 2359296
#define OFF_W2    11077632u     // 1024*768*2 = 1572864
#define OFF_B1    12650496u     // 2048*4
#define OFF_B2    12658688u     // 1024*4
#define OFF_FC1W  12662784u     // 128*512*2 = 131072
#define OFF_FC2W  12793856u     // 64*128*2 = 16384
#define OFF_HS2   12810240u     // 64*1024*256*2 = 33554432
#define OFF_HST   46364672u     // 33554432 -> end ~80 MB

// barrier field offsets (in unsigned words, 256 B apart to separate lines)
#define BAR_L1CNT   0
#define BAR_L1SENSE 64
#define BAR_L1DONE  128
#define BAR_L2CNT   192
#define BAR_L2SENSE 256
#define BAR_L2PROG  320

__device__ __forceinline__ bf16x8 ld16(const bf16_t* p) {
  u32x4 u = *reinterpret_cast<const u32x4*>(p);
  return __builtin_bit_cast(bf16x8, u);
}
__device__ __forceinline__ f32x4 mfma_bf16(bf16x8 a, bf16x8 b, f32x4 c) {
  return __builtin_amdgcn_mfma_f32_16x16x32_bf16(a, b, c, 0, 0, 0);
}
__device__ __forceinline__ float sigf(float x) { return 1.f / (1.f + __expf(-x)); }
__device__ __forceinline__ float tanh_fast(float x) {
  float e = __expf(-2.f * fabsf(x));
  float r = (1.f - e) / (1.f + e);
  return x < 0.f ? -r : r;
}
__device__ __forceinline__ void st_bf16_nt(bf16_t* p, float v) {
  __hip_bfloat16 b = __float2bfloat16(v);
  unsigned short u = *reinterpret_cast<unsigned short*>(&b);
  __builtin_nontemporal_store(u, reinterpret_cast<unsigned short*>(p));
}

// ---------------- setup: bf16 conversion / packing ----------------
__global__ void setup_kernel(const float* __restrict__ x,
    const float* __restrict__ Wih1, const float* __restrict__ Whh1,
    const float* __restrict__ bih1, const float* __restrict__ bhh1,
    const float* __restrict__ Wih2, const float* __restrict__ Whh2,
    const float* __restrict__ bih2, const float* __restrict__ bhh2,
    const float* __restrict__ fc1w, const float* __restrict__ fc2w,
    char* __restrict__ ws)
{
  bf16_t* xb = (bf16_t*)(ws + OFF_XB);
  bf16_t* w1 = (bf16_t*)(ws + OFF_W1);
  bf16_t* w2 = (bf16_t*)(ws + OFF_W2);
  float*  b1 = (float*)(ws + OFF_B1);
  float*  b2 = (float*)(ws + OFF_B2);
  bf16_t* f1 = (bf16_t*)(ws + OFF_FC1W);
  bf16_t* f2 = (bf16_t*)(ws + OFF_FC2W);
  const long E0 = 4194304, E1 = E0 + 1179648, E2 = E1 + 786432,
             E3 = E2 + 2048, E4 = E3 + 1024, E5 = E4 + 65536, E6 = E5 + 8192;
  for (long i = blockIdx.x * (long)blockDim.x + threadIdx.x; i < E6;
       i += (long)gridDim.x * blockDim.x) {
    if (i < E0) {
      xb[i] = __float2bfloat16(x[i]);
    } else if (i < E1) {                       // W1[j][k] = concat(Wih1, Whh1) rows
      long idx = i - E0; long j = idx / 576, k = idx % 576;
      float v = (k < 64) ? Wih1[j * 64 + k] : Whh1[j * 512 + (k - 64)];
      w1[idx] = __float2bfloat16(v);
    } else if (i < E2) {                       // W2[j][k] = concat(Wih2, Whh2)
      long idx = i - E1; long j = idx / 768, k = idx % 768;
      float v = (k < 512) ? Wih2[j * 512 + k] : Whh2[j * 256 + (k - 512)];
      w2[idx] = __float2bfloat16(v);
    } else if (i < E3) {
      long idx = i - E2; b1[idx] = bih1[idx] + bhh1[idx];
    } else if (i < E4) {
      long idx = i - E3; b2[idx] = bih2[idx] + bhh2[idx];
    } else if (i < E5) {
      long idx = i - E4; f1[idx] = __float2bfloat16(fc1w[idx]);
    } else {                                   // fc2 padded to 64 rows
      long idx = i - E5; long j = idx / 128, k = idx % 128;
      f2[idx] = __float2bfloat16(j < 51 ? fc2w[j * 128 + k] : 0.f);
    }
  }
}

// ---------------- group barrier with published progress ----------------
// Chain: member stores -> member acq_rel RMW on cnt -> (RMW chain) -> finisher
// acq_rel RMW -> finisher release-stores pub & sense -> waiter acquire-load.
__device__ __forceinline__ void group_barrier_publish(unsigned* cnt, unsigned* sense,
                                                      unsigned* pub, unsigned gen,
                                                      unsigned members) {
  __syncthreads();
  if (threadIdx.x == 0) {
    unsigned old = __hip_atomic_fetch_add(cnt, 1u, __ATOMIC_ACQ_REL, __HIP_MEMORY_SCOPE_AGENT);
    if (old == members - 1) {
      __hip_atomic_store(cnt, 0u, __ATOMIC_RELAXED, __HIP_MEMORY_SCOPE_AGENT);
      __hip_atomic_store(pub, gen, __ATOMIC_RELEASE, __HIP_MEMORY_SCOPE_AGENT);
      __hip_atomic_store(sense, gen, __ATOMIC_RELEASE, __HIP_MEMORY_SCOPE_AGENT);
    } else {
      unsigned s;
      do {
        __builtin_amdgcn_s_sleep(1);
        s = __hip_atomic_load(sense, __ATOMIC_ACQUIRE, __HIP_MEMORY_SCOPE_AGENT);
      } while (s < gen);
    }
  }
  __syncthreads();
}

// thread0 spins until *ptr >= need (acquire), then block-wide sync
__device__ __forceinline__ void wait_ge(unsigned* ptr, int need) {
  if (threadIdx.x == 0 && need > 0) {
    unsigned s;
    do {
      __builtin_amdgcn_s_sleep(1);
      s = __hip_atomic_load(ptr, __ATOMIC_ACQUIRE, __HIP_MEMORY_SCOPE_AGENT);
    } while ((int)s < need);
  }
  __syncthreads();
}

// ---------------- persistent LSTM kernel (both layers, decoupled pipelines) ------
__global__ __launch_bounds__(256, 1) void lstm_kernel(char* __restrict__ ws,
                                                      float* __restrict__ dout)
{
  const bf16_t* xb  = (const bf16_t*)(ws + OFF_XB);
  const bf16_t* W1  = (const bf16_t*)(ws + OFF_W1);
  const bf16_t* W2  = (const bf16_t*)(ws + OFF_W2);
  const float*  b1  = (const float*)(ws + OFF_B1);
  const float*  b2  = (const float*)(ws + OFF_B2);
  bf16_t* h1b = (bf16_t*)(ws + OFF_H1B);      // 4-deep ring
  bf16_t* h2b = (bf16_t*)(ws + OFF_H2B);      // 2-deep ring
  bf16_t* hs2 = (bf16_t*)(ws + OFF_HS2);
  unsigned* bar = (unsigned*)(ws + OFF_BAR);

  __shared__ float gbuf[4][64][32];   // 32 KB: gates (fp32) for 64 batch x 32 units

  const int tid  = threadIdx.x;
  const int wave = tid >> 6;
  const int lane = tid & 63;
  const int l15  = lane & 15;
  const int quad = lane >> 4;
  const int wg   = blockIdx.x;
  const f32x4 z = {0.f, 0.f, 0.f, 0.f};

  if (wg < NB1) {
    // ---- LSTM layer 1: block owns 32 units [u0, u0+32), wave = gate
    const int u0 = wg * 32;
    bf16x8 wf[18][2];
    #pragma unroll
    for (int i = 0; i < 18; ++i) {
      int k = (i < 2) ? i * 32 : 64 + (i - 2) * 32;
      #pragma unroll
      for (int nt = 0; nt < 2; ++nt)
        wf[i][nt] = ld16(W1 + (size_t)(wave * H1_ + u0 + nt * 16 + l15) * K1_ + k + quad * 8);
    }
    int ub[8], uu[8];
    float bi[8], bff[8], bg[8], bo[8], creg[8];
    #pragma unroll
    for (int r = 0; r < 8; ++r) {
      int idx = tid + r * 256;
      ub[r] = idx >> 5;
      uu[r] = u0 + (idx & 31);
      bi[r]  = b1[uu[r]];
      bff[r] = b1[H1_ + uu[r]];
      bg[r]  = b1[2 * H1_ + uu[r]];
      bo[r]  = b1[3 * H1_ + uu[r]];
      creg[r] = 0.f;
    }
    #pragma unroll 1
    for (int t = 0; t < T_; ++t) {
      // back-pressure: overwriting h1b[t&3] (step t-4 data) needs l2_prog >= t-3
      wait_ge(bar + BAR_L2PROG, t - 3);
      const bf16_t* hprev = h1b + ((t - 1) & 3) * (N_ * H1_);
      bf16_t* hcur = h1b + (t & 3) * (N_ * H1_);
      f32x4 acc[4][2];
      #pragma unroll
      for (int mt = 0; mt < 4; ++mt) { acc[mt][0] = z; acc[mt][1] = z; }
      #pragma unroll
      for (int ki = 0; ki < 2; ++ki) {
        #pragma unroll
        for (int mt = 0; mt < 4; ++mt) {
          bf16x8 aw = ld16(xb + ((size_t)(mt * 16 + l15) * T_ + t) * IN_ + ki * 32 + quad * 8);
          #pragma unroll
          for (int nt = 0; nt < 2; ++nt)
            acc[mt][nt] = mfma_bf16(aw, wf[ki][nt], acc[mt][nt]);
        }
      }
      #pragma unroll
      for (int ki = 0; ki < 16; ++ki) {
        #pragma unroll
        for (int mt = 0; mt < 4; ++mt) {
          bf16x8 aw = ld16(hprev + (size_t)(mt * 16 + l15) * H1_ + ki * 32 + quad * 8);
          #pragma unroll
          for (int nt = 0; nt < 2; ++nt)
            acc[mt][nt] = mfma_bf16(aw, wf[2 + ki][nt], acc[mt][nt]);
        }
      }
      #pragma unroll
      for (int mt = 0; mt < 4; ++mt)
        #pragma unroll
        for (int nt = 0; nt < 2; ++nt)
          #pragma unroll
          for (int r = 0; r < 4; ++r)
            gbuf[wave][mt * 16 + quad * 4 + r][nt * 16 + l15] = acc[mt][nt][r];
      __syncthreads();
      #pragma unroll
      for (int r = 0; r < 8; ++r) {
        int b = ub[r], ug = uu[r], u = ug - u0;
        float iv = sigf(gbuf[0][b][u] + bi[r]);
        float fv = sigf(gbuf[1][b][u] + bff[r]);
        float gv = tanh_fast(gbuf[2][b][u] + bg[r]);
        float ov = sigf(gbuf[3][b][u] + bo[r]);
        float c = fv * creg[r] + iv * gv;
        creg[r] = c;
        float h = ov * tanh_fast(c);
        hcur[(size_t)b * H1_ + ug] = __float2bfloat16(h);   // cached store (L2/L3-serviceable)
        if (t == T_ - 1) {
          dout[65536 + b * H1_ + ug] = h;
          dout[98304 + b * H1_ + ug] = c;
        }
      }
      // 16-way barrier among L1 blocks; finisher publishes l1_done = t+1
      group_barrier_publish(bar + BAR_L1CNT, bar + BAR_L1SENSE,
                            bar + BAR_L1DONE, (unsigned)(t + 1), NB1);
    }
  } else {
    // ---- LSTM layer 2: block owns 32 units, runs its own t-loop behind L1
    const int wg2 = wg - NB1;
    const int u0 = wg2 * 32;
    bf16x8 wf[24][2];
    #pragma unroll
    for (int i = 0; i < 24; ++i) {
      int k = (i < 16) ? i * 32 : 512 + (i - 16) * 32;
      #pragma unroll
      for (int nt = 0; nt < 2; ++nt)
        wf[i][nt] = ld16(W2 + (size_t)(wave * H2_ + u0 + nt * 16 + l15) * K2_ + k + quad * 8);
    }
    int ub[8], uu[8];
    float bi[8], bff[8], bg[8], bo[8], creg[8];
    #pragma unroll
    for (int r = 0; r < 8; ++r) {
      int idx = tid + r * 256;
      ub[r] = idx >> 5;
      uu[r] = u0 + (idx & 31);
      bi[r]  = b2[uu[r]];
      bff[r] = b2[H2_ + uu[r]];
      bg[r]  = b2[2 * H2_ + uu[r]];
      bo[r]  = b2[3 * H2_ + uu[r]];
      creg[r] = 0.f;
    }
    #pragma unroll 1
    for (int t = 0; t < T_; ++t) {
      // need h1(t) published
      wait_ge(bar + BAR_L1DONE, t + 1);
      const bf16_t* xin   = h1b + (t & 3) * (N_ * H1_);
      const bf16_t* hprev = h2b + ((t - 1) & 1) * (N_ * H2_);
      bf16_t* hcur = h2b + (t & 1) * (N_ * H2_);
      f32x4 acc[4][2];
      #pragma unroll
      for (int mt = 0; mt < 4; ++mt) { acc[mt][0] = z; acc[mt][1] = z; }
      #pragma unroll
      for (int ki = 0; ki < 16; ++ki) {
        #pragma unroll
        for (int mt = 0; mt < 4; ++mt) {
          bf16x8 aw = ld16(xin + (size_t)(mt * 16 + l15) * H1_ + ki * 32 + quad * 8);
          #pragma unroll
          for (int nt = 0; nt < 2; ++nt)
            acc[mt][nt] = mfma_bf16(aw, wf[ki][nt], acc[mt][nt]);
        }
      }
      #pragma unroll
      for (int ki = 0; ki < 8; ++ki) {
        #pragma unroll
        for (int mt = 0; mt < 4; ++mt) {
          bf16x8 aw = ld16(hprev + (size_t)(mt * 16 + l15) * H2_ + ki * 32 + quad * 8);
          #pragma unroll
          for (int nt = 0; nt < 2; ++nt)
            acc[mt][nt] = mfma_bf16(aw, wf[16 + ki][nt], acc[mt][nt]);
        }
      }
      #pragma unroll
      for (int mt = 0; mt < 4; ++mt)
        #pragma unroll
        for (int nt = 0; nt < 2; ++nt)
          #pragma unroll
          for (int r = 0; r < 4; ++r)
            gbuf[wave][mt * 16 + quad * 4 + r][nt * 16 + l15] = acc[mt][nt][r];
      __syncthreads();
      #pragma unroll
      for (int r = 0; r < 8; ++r) {
        int b = ub[r], ug = uu[r], u = ug - u0;
        float iv = sigf(gbuf[0][b][u] + bi[r]);
        float fv = sigf(gbuf[1][b][u] + bff[r]);
        float gv = tanh_fast(gbuf[2][b][u] + bg[r]);
        float ov = sigf(gbuf[3][b][u] + bo[r]);
        float c = fv * creg[r] + iv * gv;
        creg[r] = c;
        float h = ov * tanh_fast(c);
        hcur[(size_t)b * H2_ + ug] = __float2bfloat16(h);      // cached (recurrent)
        st_bf16_nt(hs2 + ((size_t)b * T_ + t) * H2_ + ug, h);  // streamed (read later)
        if (t == T_ - 1) {
          dout[131072 + b * H2_ + ug] = h;
          dout[147456 + b * H2_ + ug] = c;
        }
      }
      // 8-way barrier among L2 blocks; finisher publishes l2_prog = t+1
      group_barrier_publish(bar + BAR_L2CNT, bar + BAR_L2SENSE,
                            bar + BAR_L2PROG, (unsigned)(t + 1), NB2);
    }
  }
}

// ---------------- hs2 [n][t][ch] -> hsT [n][ch][t]  (LDS tile transpose) ----------------
__global__ __launch_bounds__(256) void transpose_kernel(char* __restrict__ ws)
{
  const unsigned short* src = (const unsigned short*)(ws + OFF_HS2);
  unsigned short* dst = (unsigned short*)(ws + OFF_HST);
  __shared__ unsigned short tile[64][72];
  const int bx = blockIdx.x;
  const int n  = bx >> 6;
  const int tt = (bx & 63) >> 2;
  const int cb = bx & 3;
  const int t0 = tt * 64, c0 = cb * 64;
  const int tid = threadIdx.x;
  const int row = tid >> 3;          // 0..31
  const int colg = (tid & 7) * 8;    // 0,8,..,56
  #pragma unroll
  for (int i = 0; i < 2; ++i) {
    int r = row + i * 32;
    u16x8 v = *reinterpret_cast<const u16x8*>(src + ((size_t)n * T_ + t0 + r) * H2_ + c0 + colg);
    *reinterpret_cast<u16x8*>(&tile[r][colg]) = v;
  }
  __syncthreads();
  #pragma unroll
  for (int i = 0; i < 2; ++i) {
    int crow = row + i * 32;
    u16x8 v;
    #pragma unroll
    for (int j = 0; j < 8; ++j) v[j] = tile[colg + j][crow];
    *reinterpret_cast<u16x8*>(dst + ((size_t)n * H2_ + c0 + crow) * T_ + t0 + colg) = v;
  }
}

// ---------------- flash attention + fused FC head ----------------
__global__ __launch_bounds__(256, 2) void attn_fc_kernel(
    const char* __restrict__ ws,
    const float* __restrict__ fc1b, const float* __restrict__ fc2b,
    const float* __restrict__ fc3w, const float* __restrict__ fc3b,
    float* __restrict__ dout)
{
  const bf16_t* hs2 = (const bf16_t*)(ws + OFF_HS2);
  const bf16_t* hsT = (const bf16_t*)(ws + OFF_HST);
  const bf16_t* f1w = (const bf16_t*)(ws + OFF_FC1W);
  const bf16_t* f2w = (const bf16_t*)(ws + OFF_FC2W);

  __shared__ __align__(16) unsigned char smem[51200];
  bf16_t* ctxlds = (bf16_t*)smem;             // [64][264]
  bf16_t* act1   = (bf16_t*)(smem + 33792);   // [64][136]
  bf16_t* plds   = (bf16_t*)(smem + 33792);   // wave w: +w*1152, [16][72]
  float*  act2   = (float*)smem;              // [64][68]

  const int tid  = threadIdx.x;
  const int wave = tid >> 6, lane = tid & 63;
  const int l15  = lane & 15, quad = lane >> 4;
  const int n  = blockIdx.x >> 4;
  const int qt = blockIdx.x & 15;
  const int q0 = qt * 64;
  const f32x4 z = {0.f, 0.f, 0.f, 0.f};

  bf16x8 aq[8];
  #pragma unroll
  for (int ks = 0; ks < 8; ++ks)
    aq[ks] = ld16(hs2 + ((size_t)n * T_ + q0 + wave * 16 + l15) * H2_ + ks * 32 + quad * 8);

  f32x4 o[16];
  #pragma unroll
  for (int ct = 0; ct < 16; ++ct) o[ct] = z;
  float m_run[4], l_run[4];
  #pragma unroll
  for (int r = 0; r < 4; ++r) { m_run[r] = -1e30f; l_run[r] = 0.f; }

  bf16_t* pw = plds + wave * 1152;

  #pragma unroll 1
  for (int st = 0; st <= qt; ++st) {
    const int s0 = st * 64;
    f32x4 sc[4] = {z, z, z, z};
    #pragma unroll
    for (int ks = 0; ks < 8; ++ks) {
      #pragma unroll
      for (int nt = 0; nt < 4; ++nt) {
        bf16x8 bk = ld16(hs2 + ((size_t)n * T_ + s0 + nt * 16 + l15) * H2_ + ks * 32 + quad * 8);
        sc[nt] = mfma_bf16(aq[ks], bk, sc[nt]);
      }
    }
    if (st == qt) {
      int qg = q0 + wave * 16 + quad * 4;
      #pragma unroll
      for (int nt = 0; nt < 4; ++nt) {
        int sg = s0 + nt * 16 + l15;
        #pragma unroll
        for (int r = 0; r < 4; ++r)
          if (sg > qg + r) sc[nt][r] = -1e30f;
      }
    }
    float alpha[4];
    #pragma unroll
    for (int r = 0; r < 4; ++r) {
      float tm = fmaxf(fmaxf(sc[0][r], sc[1][r]), fmaxf(sc[2][r], sc[3][r]));
      tm = fmaxf(tm, __shfl_xor(tm, 1, 16));
      tm = fmaxf(tm, __shfl_xor(tm, 2, 16));
      tm = fmaxf(tm, __shfl_xor(tm, 4, 16));
      tm = fmaxf(tm, __shfl_xor(tm, 8, 16));
      float mnew = fmaxf(m_run[r], tm);
      alpha[r] = __expf(m_run[r] - mnew);
      m_run[r] = mnew;
      float ts = 0.f;
      #pragma unroll
      for (int nt = 0; nt < 4; ++nt) {
        float p = __expf(sc[nt][r] - mnew);
        sc[nt][r] = p;
        ts += p;
      }
      ts += __shfl_xor(ts, 1, 16);
      ts += __shfl_xor(ts, 2, 16);
      ts += __shfl_xor(ts, 4, 16);
      ts += __shfl_xor(ts, 8, 16);
      l_run[r] = l_run[r] * alpha[r] + ts;
    }
    #pragma unroll
    for (int ct = 0; ct < 16; ++ct)
      #pragma unroll
      for (int r = 0; r < 4; ++r)
        o[ct][r] *= alpha[r];
    #pragma unroll
    for (int nt = 0; nt < 4; ++nt)
      #pragma unroll
      for (int r = 0; r < 4; ++r)
        pw[(quad * 4 + r) * 72 + nt * 16 + l15] = __float2bfloat16(sc[nt][r]);
    #pragma unroll
    for (int ks2 = 0; ks2 < 2; ++ks2) {
      bf16x8 ap = ld16(pw + l15 * 72 + ks2 * 32 + quad * 8);
      #pragma unroll
      for (int ct = 0; ct < 16; ++ct) {
        bf16x8 bv = ld16(hsT + ((size_t)n * H2_ + ct * 16 + l15) * T_ + s0 + ks2 * 32 + quad * 8);
        o[ct] = mfma_bf16(ap, bv, o[ct]);
      }
    }
  }
  float inv[4];
  #pragma unroll
  for (int r = 0; r < 4; ++r) inv[r] = 1.f / l_run[r];
  #pragma unroll
  for (int ct = 0; ct < 16; ++ct)
    #pragma unroll
    for (int r = 0; r < 4; ++r)
      ctxlds[(wave * 16 + quad * 4 + r) * 264 + ct * 16 + l15] =
          __float2bfloat16(o[ct][r] * inv[r]);
  __syncthreads();

  // fc1: K=512 (ctx|hs2) -> 128 ch, wave owns 32 channels
  f32x4 a1[4][2];
  #pragma unroll
  for (int mt = 0; mt < 4; ++mt) { a1[mt][0] = z; a1[mt][1] = z; }
  #pragma unroll
  for (int ks = 0; ks < 16; ++ks) {
    bf16x8 af[4];
    if (ks < 8) {
      #pragma unroll
      for (int mt = 0; mt < 4; ++mt)
        af[mt] = ld16(ctxlds + (mt * 16 + l15) * 264 + ks * 32 + quad * 8);
    } else {
      #pragma unroll
      for (int mt = 0; mt < 4; ++mt)
        af[mt] = ld16(hs2 + ((size_t)n * T_ + q0 + mt * 16 + l15) * H2_ + (ks - 8) * 32 + quad * 8);
    }
    #pragma unroll
    for (int nt = 0; nt < 2; ++nt) {
      bf16x8 bw = ld16(f1w + (size_t)(wave * 32 + nt * 16 + l15) * 512 + ks * 32 + quad * 8);
      #pragma unroll
      for (int mt = 0; mt < 4; ++mt)
        a1[mt][nt] = mfma_bf16(af[mt], bw, a1[mt][nt]);
    }
  }
  #pragma unroll
  for (int mt = 0; mt < 4; ++mt)
    #pragma unroll
    for (int nt = 0; nt < 2; ++nt)
      #pragma unroll
      for (int r = 0; r < 4; ++r) {
        int ch = wave * 32 + nt * 16 + l15;
        float v = a1[mt][nt][r] + fc1b[ch];
        act1[(mt * 16 + quad * 4 + r) * 136 + ch] = __float2bfloat16(fmaxf(v, 0.f));
      }
  __syncthreads();

  // fc2: K=128 -> 51 ch (padded 64), wave owns 16 channels
  f32x4 a2[4] = {z, z, z, z};
  #pragma unroll
  for (int ks = 0; ks < 4; ++ks) {
    bf16x8 bw = ld16(f2w + (wave * 16 + l15) * 128 + ks * 32 + quad * 8);
    #pragma unroll
    for (int mt = 0; mt < 4; ++mt) {
      bf16x8 af = ld16(act1 + (mt * 16 + l15) * 136 + ks * 32 + quad * 8);
      a2[mt] = mfma_bf16(af, bw, a2[mt]);
    }
  }
  #pragma unroll
  for (int mt = 0; mt < 4; ++mt)
    #pragma unroll
    for (int r = 0; r < 4; ++r) {
      int ch = wave * 16 + l15;
      int row = mt * 16 + quad * 4 + r;
      float v = a2[mt][r] + (ch < 51 ? fc2b[ch] : 0.f);
      act2[row * 68 + ch] = fmaxf(v, 0.f);
    }
  __syncthreads();

  // fc3: dot over 51
  if (tid < 64) {
    float s = fc3b[0];
    for (int c = 0; c < 51; ++c) s += act2[tid * 68 + c] * fc3w[c];
    dout[(size_t)n * T_ + q0 + tid] = s;
  }
}

extern "C" void kernel_launch(void* const* d_in, const int* in_sizes, int n_in,
                              void* d_out, int out_size, void* d_ws, size_t ws_size,
                              hipStream_t stream) {
  (void)in_sizes; (void)n_in; (void)out_size; (void)ws_size;
  const float* x    = (const float*)d_in[0];
  const float* Wih1 = (const float*)d_in[1];
  const float* Whh1 = (const float*)d_in[2];
  const float* bih1 = (const float*)d_in[3];
  const float* bhh1 = (const float*)d_in[4];
  const float* Wih2 = (const float*)d_in[5];
  const float* Whh2 = (const float*)d_in[6];
  const float* bih2 = (const float*)d_in[7];
  const float* bhh2 = (const float*)d_in[8];
  const float* fc1w = (const float*)d_in[9];
  const float* fc1b = (const float*)d_in[10];
  const float* fc2w = (const float*)d_in[11];
  const float* fc2b = (const float*)d_in[12];
  const float* fc3w = (const float*)d_in[13];
  const float* fc3b = (const float*)d_in[14];
  char* ws  = (char*)d_ws;
  float* out = (float*)d_out;

  hipMemsetAsync(ws, 0, ZERO_BYTES, stream);   // h rings + barrier state
  setup_kernel<<<2048, 256, 0, stream>>>(x, Wih1, Whh1, bih1, bhh1,
                                         Wih2, Whh2, bih2, bhh2, fc1w, fc2w, ws);
  lstm_kernel<<<NBLK, 256, 0, stream>>>(ws, out);
  transpose_kernel<<<4096, 256, 0, stream>>>(ws);
  attn_fc_kernel<<<1024, 256, 0, stream>>>(ws, fc1b, fc2b, fc3w, fc3b, out);
}

// Round 4
// 20381.467 us; speedup vs baseline: 1.2229x; 1.0057x over previous
//
#include <hip/hip_runtime.h>
#include <hip/hip_bf16.h>

#define N_   64
#define T_   1024
#define IN_  64
#define H1_  512
#define H2_  256
#define K1_  576    // IN_ + H1_
#define K2_  768    // H1_ + H2_
#define NBLK 24     // 16 layer-1 blocks + 8 layer-2 blocks
#define NB1  16
#define NB2  8

typedef __bf16 bf16x8 __attribute__((ext_vector_type(8)));
typedef float  f32x4  __attribute__((ext_vector_type(4)));
typedef unsigned int u32x4 __attribute__((ext_vector_type(4)));
typedef unsigned short u16x8 __attribute__((ext_vector_type(8)));
typedef __hip_bfloat16 bf16_t;

// ---------------- workspace layout (bytes) ----------------
#define OFF_H1B   0u            // 4-deep ring: 4 * 64*512*2 = 262144
#define OFF_H2B   262144u       // 2-deep:      2 * 64*256*2 = 65536
#define OFF_BAR   327680u       // flag area: 24 flags x 128 B = 3072
#define ZERO_BYTES 330752u
#define OFF_XB    330752u       // 64*1024*64*2 = 8388608
#define OFF_W1    8719360u      // 2048*576*2 = 2359296
#define OFF_W2    11078656u     // 1024*768*2 = 1572864
#define OFF_B1    12651520u     // 2048*4 (pad 8192)
#define OFF_B2    12659712u     // 1024*4 (pad 4096)
#define OFF_FC1W  12663808u     // 128*512*2 = 131072
#define OFF_FC2W  12794880u     // 64*128*2 = 16384
#define OFF_HS2   12811264u     // 64*1024*256*2 = 33554432
#define OFF_HST   46365696u     // 33554432 -> end ~80 MB

__device__ __forceinline__ bf16x8 ld16(const bf16_t* p) {
  u32x4 u = *reinterpret_cast<const u32x4*>(p);
  return __builtin_bit_cast(bf16x8, u);
}
__device__ __forceinline__ f32x4 mfma_bf16(bf16x8 a, bf16x8 b, f32x4 c) {
  return __builtin_amdgcn_mfma_f32_16x16x32_bf16(a, b, c, 0, 0, 0);
}
__device__ __forceinline__ float sigf(float x) { return 1.f / (1.f + __expf(-x)); }
__device__ __forceinline__ float tanh_fast(float x) {
  float e = __expf(-2.f * fabsf(x));
  float r = (1.f - e) / (1.f + e);
  return x < 0.f ? -r : r;
}

// ---------------- setup: bf16 conversion / packing ----------------
__global__ void setup_kernel(const float* __restrict__ x,
    const float* __restrict__ Wih1, const float* __restrict__ Whh1,
    const float* __restrict__ bih1, const float* __restrict__ bhh1,
    const float* __restrict__ Wih2, const float* __restrict__ Whh2,
    const float* __restrict__ bih2, const float* __restrict__ bhh2,
    const float* __restrict__ fc1w, const float* __restrict__ fc2w,
    char* __restrict__ ws)
{
  bf16_t* xb = (bf16_t*)(ws + OFF_XB);
  bf16_t* w1 = (bf16_t*)(ws + OFF_W1);
  bf16_t* w2 = (bf16_t*)(ws + OFF_W2);
  float*  b1 = (float*)(ws + OFF_B1);
  float*  b2 = (float*)(ws + OFF_B2);
  bf16_t* f1 = (bf16_t*)(ws + OFF_FC1W);
  bf16_t* f2 = (bf16_t*)(ws + OFF_FC2W);
  const long E0 = 4194304, E1 = E0 + 1179648, E2 = E1 + 786432,
             E3 = E2 + 2048, E4 = E3 + 1024, E5 = E4 + 65536, E6 = E5 + 8192;
  for (long i = blockIdx.x * (long)blockDim.x + threadIdx.x; i < E6;
       i += (long)gridDim.x * blockDim.x) {
    if (i < E0) {
      xb[i] = __float2bfloat16(x[i]);
    } else if (i < E1) {                       // W1[j][k] = concat(Wih1, Whh1) rows
      long idx = i - E0; long j = idx / 576, k = idx % 576;
      float v = (k < 64) ? Wih1[j * 64 + k] : Whh1[j * 512 + (k - 64)];
      w1[idx] = __float2bfloat16(v);
    } else if (i < E2) {                       // W2[j][k] = concat(Wih2, Whh2)
      long idx = i - E1; long j = idx / 768, k = idx % 768;
      float v = (k < 512) ? Wih2[j * 512 + k] : Whh2[j * 256 + (k - 512)];
      w2[idx] = __float2bfloat16(v);
    } else if (i < E3) {
      long idx = i - E2; b1[idx] = bih1[idx] + bhh1[idx];
    } else if (i < E4) {
      long idx = i - E3; b2[idx] = bih2[idx] + bhh2[idx];
    } else if (i < E5) {
      long idx = i - E4; f1[idx] = __float2bfloat16(fc1w[idx]);
    } else {                                   // fc2 padded to 64 rows
      long idx = i - E5; long j = idx / 128, k = idx % 128;
      f2[idx] = __float2bfloat16(j < 51 ? fc2w[j * 128 + k] : 0.f);
    }
  }
}

// ---------------- flag sync: relaxed wave-parallel poll, one acquire ----------------
// f1: 16 flags (stride 32 words = 128 B); f2: 8 flags. Lane i<16 polls f1[i]>=need1,
// lanes 16..23 poll f2[i-16]>=need2. RELAXED polls (no L2 invalidate per iteration);
// a single ACQUIRE load after success pairs with producers' releases + invalidates L2.
__device__ __forceinline__ void poll_flags(unsigned* f1, unsigned* f2,
                                           int need1, int need2) {
  if (threadIdx.x < 64) {
    const int lane = threadIdx.x;
    unsigned* p = nullptr;
    int need = 0;
    if (lane < NB1)              { p = f1 + lane * 32;        need = need1; }
    else if (lane < NB1 + NB2)   { p = f2 + (lane - NB1) * 32; need = need2; }
    bool ok = (p == nullptr) || (need <= 0);
    if (!ok)
      ok = ((int)__hip_atomic_load(p, __ATOMIC_RELAXED, __HIP_MEMORY_SCOPE_AGENT) >= need);
    while (!__all(ok)) {
      __builtin_amdgcn_s_sleep(1);
      if (p && need > 0)
        ok = ((int)__hip_atomic_load(p, __ATOMIC_RELAXED, __HIP_MEMORY_SCOPE_AGENT) >= need);
      else
        ok = true;
    }
    if (p)  // one wave-level acquire (single buffer_inv), pairs with releases
      (void)__hip_atomic_load(p, __ATOMIC_ACQUIRE, __HIP_MEMORY_SCOPE_AGENT);
  }
  __syncthreads();
}

__device__ __forceinline__ void publish_flag(unsigned* slot, unsigned gen) {
  // caller must __syncthreads() first (all block stores drained to L2 by the
  // pre-barrier vmcnt(0)); the agent release writes back dirty L2 then stores.
  if (threadIdx.x == 0)
    __hip_atomic_store(slot, gen, __ATOMIC_RELEASE, __HIP_MEMORY_SCOPE_AGENT);
}

// ---------------- persistent LSTM kernel (both layers, flag-synced) ----------------
__global__ __launch_bounds__(256, 1) void lstm_kernel(char* __restrict__ ws,
                                                      float* __restrict__ dout)
{
  const bf16_t* xb  = (const bf16_t*)(ws + OFF_XB);
  const bf16_t* W1  = (const bf16_t*)(ws + OFF_W1);
  const bf16_t* W2  = (const bf16_t*)(ws + OFF_W2);
  const float*  b1  = (const float*)(ws + OFF_B1);
  const float*  b2  = (const float*)(ws + OFF_B2);
  bf16_t* h1b = (bf16_t*)(ws + OFF_H1B);      // 4-deep ring
  bf16_t* h2b = (bf16_t*)(ws + OFF_H2B);      // 2-deep ring
  bf16_t* hs2 = (bf16_t*)(ws + OFF_HS2);
  unsigned* flag1 = (unsigned*)(ws + OFF_BAR);          // 16 x 128 B
  unsigned* flag2 = flag1 + NB1 * 32;                   // 8 x 128 B

  __shared__ float gbuf[4][64][32];   // 32 KB: gates (fp32) for 64 batch x 32 units

  const int tid  = threadIdx.x;
  const int wave = tid >> 6;
  const int lane = tid & 63;
  const int l15  = lane & 15;
  const int quad = lane >> 4;
  const int wg   = blockIdx.x;
  const f32x4 z = {0.f, 0.f, 0.f, 0.f};

  if (wg < NB1) {
    // ---- LSTM layer 1: block owns 32 units [u0, u0+32), wave = gate
    const int u0 = wg * 32;
    bf16x8 wf[18][2];
    #pragma unroll
    for (int i = 0; i < 18; ++i) {
      int k = (i < 2) ? i * 32 : 64 + (i - 2) * 32;
      #pragma unroll
      for (int nt = 0; nt < 2; ++nt)
        wf[i][nt] = ld16(W1 + (size_t)(wave * H1_ + u0 + nt * 16 + l15) * K1_ + k + quad * 8);
    }
    int ub[8], uu[8];
    float bi[8], bff[8], bg[8], bo[8], creg[8];
    #pragma unroll
    for (int r = 0; r < 8; ++r) {
      int idx = tid + r * 256;
      ub[r] = idx >> 5;
      uu[r] = u0 + (idx & 31);
      bi[r]  = b1[uu[r]];
      bff[r] = b1[H1_ + uu[r]];
      bg[r]  = b1[2 * H1_ + uu[r]];
      bo[r]  = b1[3 * H1_ + uu[r]];
      creg[r] = 0.f;
    }
    #pragma unroll 1
    for (int t = 0; t < T_; ++t) {
      // peers' h1(t-1) visible (flag1 >= t); ring slot free (flag2 >= t-3)
      poll_flags(flag1, flag2, t, t - 3);
      const bf16_t* hprev = h1b + ((t - 1) & 3) * (N_ * H1_);
      bf16_t* hcur = h1b + (t & 3) * (N_ * H1_);
      f32x4 acc[4][2];
      #pragma unroll
      for (int mt = 0; mt < 4; ++mt) { acc[mt][0] = z; acc[mt][1] = z; }
      #pragma unroll
      for (int ki = 0; ki < 2; ++ki) {
        #pragma unroll
        for (int mt = 0; mt < 4; ++mt) {
          bf16x8 aw = ld16(xb + ((size_t)(mt * 16 + l15) * T_ + t) * IN_ + ki * 32 + quad * 8);
          #pragma unroll
          for (int nt = 0; nt < 2; ++nt)
            acc[mt][nt] = mfma_bf16(aw, wf[ki][nt], acc[mt][nt]);
        }
      }
      #pragma unroll
      for (int ki = 0; ki < 16; ++ki) {
        #pragma unroll
        for (int mt = 0; mt < 4; ++mt) {
          bf16x8 aw = ld16(hprev + (size_t)(mt * 16 + l15) * H1_ + ki * 32 + quad * 8);
          #pragma unroll
          for (int nt = 0; nt < 2; ++nt)
            acc[mt][nt] = mfma_bf16(aw, wf[2 + ki][nt], acc[mt][nt]);
        }
      }
      #pragma unroll
      for (int mt = 0; mt < 4; ++mt)
        #pragma unroll
        for (int nt = 0; nt < 2; ++nt)
          #pragma unroll
          for (int r = 0; r < 4; ++r)
            gbuf[wave][mt * 16 + quad * 4 + r][nt * 16 + l15] = acc[mt][nt][r];
      __syncthreads();
      #pragma unroll
      for (int r = 0; r < 8; ++r) {
        int b = ub[r], ug = uu[r], u = ug - u0;
        float iv = sigf(gbuf[0][b][u] + bi[r]);
        float fv = sigf(gbuf[1][b][u] + bff[r]);
        float gv = tanh_fast(gbuf[2][b][u] + bg[r]);
        float ov = sigf(gbuf[3][b][u] + bo[r]);
        float c = fv * creg[r] + iv * gv;
        creg[r] = c;
        float h = ov * tanh_fast(c);
        hcur[(size_t)b * H1_ + ug] = __float2bfloat16(h);
        if (t == T_ - 1) {
          dout[65536 + b * H1_ + ug] = h;
          dout[98304 + b * H1_ + ug] = c;
        }
      }
      __syncthreads();   // all h stores drained (vmcnt(0) at barrier) before release
      publish_flag(flag1 + wg * 32, (unsigned)(t + 1));
    }
  } else {
    // ---- LSTM layer 2: block owns 32 units, own t-loop, flag-gated behind L1
    const int wg2 = wg - NB1;
    const int u0 = wg2 * 32;
    bf16x8 wf[24][2];
    #pragma unroll
    for (int i = 0; i < 24; ++i) {
      int k = (i < 16) ? i * 32 : 512 + (i - 16) * 32;
      #pragma unroll
      for (int nt = 0; nt < 2; ++nt)
        wf[i][nt] = ld16(W2 + (size_t)(wave * H2_ + u0 + nt * 16 + l15) * K2_ + k + quad * 8);
    }
    int ub[8], uu[8];
    float bi[8], bff[8], bg[8], bo[8], creg[8];
    #pragma unroll
    for (int r = 0; r < 8; ++r) {
      int idx = tid + r * 256;
      ub[r] = idx >> 5;
      uu[r] = u0 + (idx & 31);
      bi[r]  = b2[uu[r]];
      bff[r] = b2[H2_ + uu[r]];
      bg[r]  = b2[2 * H2_ + uu[r]];
      bo[r]  = b2[3 * H2_ + uu[r]];
      creg[r] = 0.f;
    }
    #pragma unroll 1
    for (int t = 0; t < T_; ++t) {
      // h1(t) published (flag1 >= t+1); peers' h2(t-1) visible (flag2 >= t)
      poll_flags(flag1, flag2, t + 1, t);
      const bf16_t* xin   = h1b + (t & 3) * (N_ * H1_);
      const bf16_t* hprev = h2b + ((t - 1) & 1) * (N_ * H2_);
      bf16_t* hcur = h2b + (t & 1) * (N_ * H2_);
      f32x4 acc[4][2];
      #pragma unroll
      for (int mt = 0; mt < 4; ++mt) { acc[mt][0] = z; acc[mt][1] = z; }
      #pragma unroll
      for (int ki = 0; ki < 16; ++ki) {
        #pragma unroll
        for (int mt = 0; mt < 4; ++mt) {
          bf16x8 aw = ld16(xin + (size_t)(mt * 16 + l15) * H1_ + ki * 32 + quad * 8);
          #pragma unroll
          for (int nt = 0; nt < 2; ++nt)
            acc[mt][nt] = mfma_bf16(aw, wf[ki][nt], acc[mt][nt]);
        }
      }
      #pragma unroll
      for (int ki = 0; ki < 8; ++ki) {
        #pragma unroll
        for (int mt = 0; mt < 4; ++mt) {
          bf16x8 aw = ld16(hprev + (size_t)(mt * 16 + l15) * H2_ + ki * 32 + quad * 8);
          #pragma unroll
          for (int nt = 0; nt < 2; ++nt)
            acc[mt][nt] = mfma_bf16(aw, wf[16 + ki][nt], acc[mt][nt]);
        }
      }
      #pragma unroll
      for (int mt = 0; mt < 4; ++mt)
        #pragma unroll
        for (int nt = 0; nt < 2; ++nt)
          #pragma unroll
          for (int r = 0; r < 4; ++r)
            gbuf[wave][mt * 16 + quad * 4 + r][nt * 16 + l15] = acc[mt][nt][r];
      __syncthreads();
      #pragma unroll
      for (int r = 0; r < 8; ++r) {
        int b = ub[r], ug = uu[r], u = ug - u0;
        float iv = sigf(gbuf[0][b][u] + bi[r]);
        float fv = sigf(gbuf[1][b][u] + bff[r]);
        float gv = tanh_fast(gbuf[2][b][u] + bg[r]);
        float ov = sigf(gbuf[3][b][u] + bo[r]);
        float c = fv * creg[r] + iv * gv;
        creg[r] = c;
        float h = ov * tanh_fast(c);
        hcur[(size_t)b * H2_ + ug] = __float2bfloat16(h);
        hs2[((size_t)b * T_ + t) * H2_ + ug] = __float2bfloat16(h);
        if (t == T_ - 1) {
          dout[131072 + b * H2_ + ug] = h;
          dout[147456 + b * H2_ + ug] = c;
        }
      }
      __syncthreads();
      publish_flag(flag2 + wg2 * 32, (unsigned)(t + 1));
    }
  }
}

// ---------------- hs2 [n][t][ch] -> hsT [n][ch][t]  (LDS tile transpose) ----------------
__global__ __launch_bounds__(256) void transpose_kernel(char* __restrict__ ws)
{
  const unsigned short* src = (const unsigned short*)(ws + OFF_HS2);
  unsigned short* dst = (unsigned short*)(ws + OFF_HST);
  __shared__ unsigned short tile[64][72];
  const int bx = blockIdx.x;
  const int n  = bx >> 6;
  const int tt = (bx & 63) >> 2;
  const int cb = bx & 3;
  const int t0 = tt * 64, c0 = cb * 64;
  const int tid = threadIdx.x;
  const int row = tid >> 3;          // 0..31
  const int colg = (tid & 7) * 8;    // 0,8,..,56
  #pragma unroll
  for (int i = 0; i < 2; ++i) {
    int r = row + i * 32;
    u16x8 v = *reinterpret_cast<const u16x8*>(src + ((size_t)n * T_ + t0 + r) * H2_ + c0 + colg);
    *reinterpret_cast<u16x8*>(&tile[r][colg]) = v;
  }
  __syncthreads();
  #pragma unroll
  for (int i = 0; i < 2; ++i) {
    int crow = row + i * 32;
    u16x8 v;
    #pragma unroll
    for (int j = 0; j < 8; ++j) v[j] = tile[colg + j][crow];
    *reinterpret_cast<u16x8*>(dst + ((size_t)n * H2_ + c0 + crow) * T_ + t0 + colg) = v;
  }
}

// ---------------- flash attention + fused FC head ----------------
__global__ __launch_bounds__(256, 2) void attn_fc_kernel(
    const char* __restrict__ ws,
    const float* __restrict__ fc1b, const float* __restrict__ fc2b,
    const float* __restrict__ fc3w, const float* __restrict__ fc3b,
    float* __restrict__ dout)
{
  const bf16_t* hs2 = (const bf16_t*)(ws + OFF_HS2);
  const bf16_t* hsT = (const bf16_t*)(ws + OFF_HST);
  const bf16_t* f1w = (const bf16_t*)(ws + OFF_FC1W);
  const bf16_t* f2w = (const bf16_t*)(ws + OFF_FC2W);

  __shared__ __align__(16) unsigned char smem[51200];
  bf16_t* ctxlds = (bf16_t*)smem;             // [64][264]
  bf16_t* act1   = (bf16_t*)(smem + 33792);   // [64][136]
  bf16_t* plds   = (bf16_t*)(smem + 33792);   // wave w: +w*1152, [16][72]
  float*  act2   = (float*)smem;              // [64][68]

  const int tid  = threadIdx.x;
  const int wave = tid >> 6, lane = tid & 63;
  const int l15  = lane & 15, quad = lane >> 4;
  const int n  = blockIdx.x >> 4;
  const int qt = blockIdx.x & 15;
  const int q0 = qt * 64;
  const f32x4 z = {0.f, 0.f, 0.f, 0.f};

  bf16x8 aq[8];
  #pragma unroll
  for (int ks = 0; ks < 8; ++ks)
    aq[ks] = ld16(hs2 + ((size_t)n * T_ + q0 + wave * 16 + l15) * H2_ + ks * 32 + quad * 8);

  f32x4 o[16];
  #pragma unroll
  for (int ct = 0; ct < 16; ++ct) o[ct] = z;
  float m_run[4], l_run[4];
  #pragma unroll
  for (int r = 0; r < 4; ++r) { m_run[r] = -1e30f; l_run[r] = 0.f; }

  bf16_t* pw = plds + wave * 1152;

  #pragma unroll 1
  for (int st = 0; st <= qt; ++st) {
    const int s0 = st * 64;
    f32x4 sc[4] = {z, z, z, z};
    #pragma unroll
    for (int ks = 0; ks < 8; ++ks) {
      #pragma unroll
      for (int nt = 0; nt < 4; ++nt) {
        bf16x8 bk = ld16(hs2 + ((size_t)n * T_ + s0 + nt * 16 + l15) * H2_ + ks * 32 + quad * 8);
        sc[nt] = mfma_bf16(aq[ks], bk, sc[nt]);
      }
    }
    if (st == qt) {
      int qg = q0 + wave * 16 + quad * 4;
      #pragma unroll
      for (int nt = 0; nt < 4; ++nt) {
        int sg = s0 + nt * 16 + l15;
        #pragma unroll
        for (int r = 0; r < 4; ++r)
          if (sg > qg + r) sc[nt][r] = -1e30f;
      }
    }
    float alpha[4];
    #pragma unroll
    for (int r = 0; r < 4; ++r) {
      float tm = fmaxf(fmaxf(sc[0][r], sc[1][r]), fmaxf(sc[2][r], sc[3][r]));
      tm = fmaxf(tm, __shfl_xor(tm, 1, 16));
      tm = fmaxf(tm, __shfl_xor(tm, 2, 16));
      tm = fmaxf(tm, __shfl_xor(tm, 4, 16));
      tm = fmaxf(tm, __shfl_xor(tm, 8, 16));
      float mnew = fmaxf(m_run[r], tm);
      alpha[r] = __expf(m_run[r] - mnew);
      m_run[r] = mnew;
      float ts = 0.f;
      #pragma unroll
      for (int nt = 0; nt < 4; ++nt) {
        float p = __expf(sc[nt][r] - mnew);
        sc[nt][r] = p;
        ts += p;
      }
      ts += __shfl_xor(ts, 1, 16);
      ts += __shfl_xor(ts, 2, 16);
      ts += __shfl_xor(ts, 4, 16);
      ts += __shfl_xor(ts, 8, 16);
      l_run[r] = l_run[r] * alpha[r] + ts;
    }
    #pragma unroll
    for (int ct = 0; ct < 16; ++ct)
      #pragma unroll
      for (int r = 0; r < 4; ++r)
        o[ct][r] *= alpha[r];
    #pragma unroll
    for (int nt = 0; nt < 4; ++nt)
      #pragma unroll
      for (int r = 0; r < 4; ++r)
        pw[(quad * 4 + r) * 72 + nt * 16 + l15] = __float2bfloat16(sc[nt][r]);
    #pragma unroll
    for (int ks2 = 0; ks2 < 2; ++ks2) {
      bf16x8 ap = ld16(pw + l15 * 72 + ks2 * 32 + quad * 8);
      #pragma unroll
      for (int ct = 0; ct < 16; ++ct) {
        bf16x8 bv = ld16(hsT + ((size_t)n * H2_ + ct * 16 + l15) * T_ + s0 + ks2 * 32 + quad * 8);
        o[ct] = mfma_bf16(ap, bv, o[ct]);
      }
    }
  }
  float inv[4];
  #pragma unroll
  for (int r = 0; r < 4; ++r) inv[r] = 1.f / l_run[r];
  #pragma unroll
  for (int ct = 0; ct < 16; ++ct)
    #pragma unroll
    for (int r = 0; r < 4; ++r)
      ctxlds[(wave * 16 + quad * 4 + r) * 264 + ct * 16 + l15] =
          __float2bfloat16(o[ct][r] * inv[r]);
  __syncthreads();

  // fc1: K=512 (ctx|hs2) -> 128 ch, wave owns 32 channels
  f32x4 a1[4][2];
  #pragma unroll
  for (int mt = 0; mt < 4; ++mt) { a1[mt][0] = z; a1[mt][1] = z; }
  #pragma unroll
  for (int ks = 0; ks < 16; ++ks) {
    bf16x8 af[4];
    if (ks < 8) {
      #pragma unroll
      for (int mt = 0; mt < 4; ++mt)
        af[mt] = ld16(ctxlds + (mt * 16 + l15) * 264 + ks * 32 + quad * 8);
    } else {
      #pragma unroll
      for (int mt = 0; mt < 4; ++mt)
        af[mt] = ld16(hs2 + ((size_t)n * T_ + q0 + mt * 16 + l15) * H2_ + (ks - 8) * 32 + quad * 8);
    }
    #pragma unroll
    for (int nt = 0; nt < 2; ++nt) {
      bf16x8 bw = ld16(f1w + (size_t)(wave * 32 + nt * 16 + l15) * 512 + ks * 32 + quad * 8);
      #pragma unroll
      for (int mt = 0; mt < 4; ++mt)
        a1[mt][nt] = mfma_bf16(af[mt], bw, a1[mt][nt]);
    }
  }
  #pragma unroll
  for (int mt = 0; mt < 4; ++mt)
    #pragma unroll
    for (int nt = 0; nt < 2; ++nt)
      #pragma unroll
      for (int r = 0; r < 4; ++r) {
        int ch = wave * 32 + nt * 16 + l15;
        float v = a1[mt][nt][r] + fc1b[ch];
        act1[(mt * 16 + quad * 4 + r) * 136 + ch] = __float2bfloat16(fmaxf(v, 0.f));
      }
  __syncthreads();

  // fc2: K=128 -> 51 ch (padded 64), wave owns 16 channels
  f32x4 a2[4] = {z, z, z, z};
  #pragma unroll
  for (int ks = 0; ks < 4; ++ks) {
    bf16x8 bw = ld16(f2w + (wave * 16 + l15) * 128 + ks * 32 + quad * 8);
    #pragma unroll
    for (int mt = 0; mt < 4; ++mt) {
      bf16x8 af = ld16(act1 + (mt * 16 + l15) * 136 + ks * 32 + quad * 8);
      a2[mt] = mfma_bf16(af, bw, a2[mt]);
    }
  }
  #pragma unroll
  for (int mt = 0; mt < 4; ++mt)
    #pragma unroll
    for (int r = 0; r < 4; ++r) {
      int ch = wave * 16 + l15;
      int row = mt * 16 + quad * 4 + r;
      float v = a2[mt][r] + (ch < 51 ? fc2b[ch] : 0.f);
      act2[row * 68 + ch] = fmaxf(v, 0.f);
    }
  __syncthreads();

  // fc3: dot over 51
  if (tid < 64) {
    float s = fc3b[0];
    for (int c = 0; c < 51; ++c) s += act2[tid * 68 + c] * fc3w[c];
    dout[(size_t)n * T_ + q0 + tid] = s;
  }
}

extern "C" void kernel_launch(void* const* d_in, const int* in_sizes, int n_in,
                              void* d_out, int out_size, void* d_ws, size_t ws_size,
                              hipStream_t stream) {
  (void)in_sizes; (void)n_in; (void)out_size; (void)ws_size;
  const float* x    = (const float*)d_in[0];
  const float* Wih1 = (const float*)d_in[1];
  const float* Whh1 = (const float*)d_in[2];
  const float* bih1 = (const float*)d_in[3];
  const float* bhh1 = (const float*)d_in[4];
  const float* Wih2 = (const float*)d_in[5];
  const float* Whh2 = (const float*)d_in[6];
  const float* bih2 = (const float*)d_in[7];
  const float* bhh2 = (const float*)d_in[8];
  const float* fc1w = (const float*)d_in[9];
  const float* fc1b = (const float*)d_in[10];
  const float* fc2w = (const float*)d_in[11];
  const float* fc2b = (const float*)d_in[12];
  const float* fc3w = (const float*)d_in[13];
  const float* fc3b = (const float*)d_in[14];
  char* ws  = (char*)d_ws;
  float* out = (float*)d_out;

  hipMemsetAsync(ws, 0, ZERO_BYTES, stream);   // h rings + flags
  setup_kernel<<<2048, 256, 0, stream>>>(x, Wih1, Whh1, bih1, bhh1,
                                         Wih2, Whh2, bih2, bhh2, fc1w, fc2w, ws);
  lstm_kernel<<<NBLK, 256, 0, stream>>>(ws, out);
  transpose_kernel<<<4096, 256, 0, stream>>>(ws);
  attn_fc_kernel<<<1024, 256, 0, stream>>>(ws, fc1b, fc2b, fc3w, fc3b, out);
}